// Round 7
// baseline (224.070 us; speedup 1.0000x reference)
//
#include <hip/hip_runtime.h>
#include <hip/hip_bf16.h>

#define TLEN 4096
#define NINP 256
#define DD   64
#define NREP 4   // probe: rep 0 -> out, reps 1..3 -> scratch (remove next round)

// 1/sqrt(64) * log2(e): folded into WqT so softmax = exp2(s)
#define QSCALE 0.18033688011112042f

typedef __attribute__((ext_vector_type(8))) short bf16x8;
typedef __attribute__((ext_vector_type(4))) float f32x4;

union U8 { bf16x8 v; uint u[4]; };
union F32U { float f; uint u; };

__device__ inline ushort bfu(float x) {           // fp32 -> bf16 RNE
    F32U a; a.f = x;
    uint r = a.u + 0x7fffu + ((a.u >> 16) & 1u);
    return (ushort)(r >> 16);
}
// pack two positive-finite f32 -> bf16 pair (round-half-up): 3 VALU ops
__device__ inline uint pk2(float p0, float p1) {
    F32U a, b; a.f = p0; b.f = p1;
    return __builtin_amdgcn_perm(b.u + 0x8000u, a.u + 0x8000u, 0x07060302u);
}
__device__ inline bf16x8 ld16(const ushort* p) {  // 16B-aligned
    return *(const bf16x8*)p;
}
__device__ inline bf16x8 ld8x2(const ushort* p) { // 8B-aligned (padded LDS)
    U8 u;
    uint2 a = *(const uint2*)p;
    uint2 b = *(const uint2*)(p + 4);
    u.u[0] = a.x; u.u[1] = a.y; u.u[2] = b.x; u.u[3] = b.y;
    return u.v;
}

// ---------------------------------------------------------------------------
// prep: WT[m][d][k] = W_m[k][d] bf16 (Wq scaled). 48 blocks.
// ---------------------------------------------------------------------------
__global__ __launch_bounds__(256) void prep_wt(
    const float* __restrict__ Wq, const float* __restrict__ Wk,
    const float* __restrict__ Wv, ushort* __restrict__ WT)
{
    const int t = threadIdx.x;                 // = k
    const int m = blockIdx.x >> 4;
    const int d0 = (blockIdx.x & 15) * 4;
    const float* W = (m == 0) ? Wq : ((m == 1) ? Wk : Wv);
    const float scale = (m == 0) ? QSCALE : 1.0f;
    float4 v = *(const float4*)&W[t * DD + d0];
    WT[m * 16384 + (d0 + 0) * 256 + t] = bfu(v.x * scale);
    WT[m * 16384 + (d0 + 1) * 256 + t] = bfu(v.y * scale);
    WT[m * 16384 + (d0 + 2) * 256 + t] = bfu(v.z * scale);
    WT[m * 16384 + (d0 + 3) * 256 + t] = bfu(v.w * scale);
}

// ---------------------------------------------------------------------------
// QKV: MFMA bf16. 512 blocks x 32 rows (2/CU). (identical to R6 — passed)
// ---------------------------------------------------------------------------
__global__ __launch_bounds__(256, 2) void qkv_kernel(
    const float* __restrict__ y, const ushort* __restrict__ WT,
    ushort* __restrict__ Qh, ushort* __restrict__ Kh, ushort* __restrict__ VhT)
{
    __shared__ ushort Wl[64 * 260];
    __shared__ ushort tb[2304];

    const int t = threadIdx.x;
    const int w = t >> 6, lane = t & 63;
    const int quad = lane >> 4, l15 = lane & 15;
    const int rgrp = w & 1, ngrp = w >> 1;
    const int rowbase = blockIdx.x * 32;
    const int myrow = rowbase + rgrp * 16 + l15;

    bf16x8 afrag[8];
    const float* yrow = y + (size_t)myrow * NINP;
    #pragma unroll
    for (int s = 0; s < 8; ++s) {
        float4 lo = *(const float4*)&yrow[s * 32 + quad * 8];
        float4 hi = *(const float4*)&yrow[s * 32 + quad * 8 + 4];
        U8 u;
        u.u[0] = bfu(lo.x) | (uint(bfu(lo.y)) << 16);
        u.u[1] = bfu(lo.z) | (uint(bfu(lo.w)) << 16);
        u.u[2] = bfu(hi.x) | (uint(bfu(hi.y)) << 16);
        u.u[3] = bfu(hi.z) | (uint(bfu(hi.w)) << 16);
        afrag[s] = u.v;
    }

    f32x4 acc[3][2];
    #pragma unroll
    for (int m = 0; m < 3; ++m)
        #pragma unroll
        for (int nj = 0; nj < 2; ++nj)
            acc[m][nj] = f32x4{0.f, 0.f, 0.f, 0.f};

    for (int m = 0; m < 3; ++m) {
        __syncthreads();
        {
            int n = t >> 2, seg = t & 3;
            const ushort* src = WT + m * 16384 + n * 256 + seg * 64;
            ushort* dst = &Wl[n * 260 + seg * 64];
            #pragma unroll
            for (int j = 0; j < 16; ++j)
                ((uint2*)dst)[j] = ((const uint2*)src)[j];
        }
        __syncthreads();
        #pragma unroll
        for (int s = 0; s < 8; ++s)
            #pragma unroll
            for (int nj = 0; nj < 2; ++nj) {
                int nt = ngrp * 2 + nj;
                bf16x8 bfrag = ld8x2(&Wl[(nt * 16 + l15) * 260 + s * 32 + quad * 8]);
                acc[m][nj] = __builtin_amdgcn_mfma_f32_16x16x32_bf16(
                    afrag[s], bfrag, acc[m][nj], 0, 0, 0);
            }
    }

    for (int m = 0; m < 2; ++m) {
        __syncthreads();
        #pragma unroll
        for (int nj = 0; nj < 2; ++nj) {
            int nt = ngrp * 2 + nj;
            #pragma unroll
            for (int r = 0; r < 4; ++r)
                tb[(rgrp * 16 + quad * 4 + r) * 68 + nt * 16 + l15] = bfu(acc[m][nj][r]);
        }
        __syncthreads();
        int row = t >> 3, c0 = (t & 7) * 8;
        ushort* gd = (m == 0 ? Qh : Kh) + (size_t)(rowbase + row) * DD + c0;
        const ushort* sp = &tb[row * 68 + c0];
        ((uint2*)gd)[0] = ((const uint2*)sp)[0];
        ((uint2*)gd)[1] = ((const uint2*)sp)[1];
    }

    __syncthreads();
    #pragma unroll
    for (int nj = 0; nj < 2; ++nj) {
        int nt = ngrp * 2 + nj;
        int d = nt * 16 + l15;
        #pragma unroll
        for (int r = 0; r < 4; r += 2) {
            int tt = rgrp * 16 + quad * 4 + r;
            *(uint*)&tb[d * 36 + tt] = pk2(acc[2][nj][r], acc[2][nj][r + 1]);
        }
    }
    __syncthreads();
    {
        int d = t >> 2, seg = t & 3;
        int bb = blockIdx.x >> 7;
        int tofs = (blockIdx.x & 127) * 32 + seg * 8;
        ushort* gv = VhT + ((size_t)bb * DD + d) * TLEN + tofs;
        const ushort* sp = &tb[d * 36 + seg * 8];
        ((uint2*)gv)[0] = ((const uint2*)sp)[0];
        ((uint2*)gv)[1] = ((const uint2*)sp)[1];
    }
}

// ---------------------------------------------------------------------------
// Attention (R6 structure) + VALU diet (l via ones-MFMA) + NREP probe loop.
// Block = one 32-q tile; grid 512; 4 waves: wave (qt=w>>1, g=w&1) owns
// 16 queries x 32 keys per 64-key chunk. K/V staged coalesced into padded
// LDS with VGPR prefetch. l_q computed on the matrix pipe: lD = mfma(P,1).
// ---------------------------------------------------------------------------
__global__ __launch_bounds__(256, 4) void attn_kernel(
    const ushort* __restrict__ Qh, const ushort* __restrict__ Kh,
    const ushort* __restrict__ VhT, float* __restrict__ out,
    float* __restrict__ outdup)
{
    __shared__ ushort Kl[64 * 72];      // [key][d] padded
    __shared__ ushort Vt[64 * 72];      // [d][key] padded
    __shared__ ushort Pw[4][16 * 36];   // per-wave P [q][k]
    __shared__ float  Ob[2][16 * 64];   // per-qt partial O (from g=1)
    __shared__ float  lb[2][16];        // per-qt partial l (from g=1)

    const int t = threadIdx.x;
    const int w = t >> 6, lane = t & 63;
    const int quad = lane >> 4, l15 = lane & 15;
    const int qt = w >> 1, g = w & 1;
    const int blk = blockIdx.x;
    const int batch = blk & 3;
    const int tile = 127 - (blk >> 2);          // big tiles first
    const int qb = tile * 32;
    const int nc = (tile + 2) >> 1;             // 64-key chunks (last masked)

    const ushort* Qb = Qh + (size_t)batch * TLEN * DD;
    const ushort* Kb = Kh + (size_t)batch * TLEN * DD;
    const ushort* Vb = VhT + (size_t)batch * DD * TLEN;

    const bf16x8 onesf = {(short)0x3f80, (short)0x3f80, (short)0x3f80, (short)0x3f80,
                          (short)0x3f80, (short)0x3f80, (short)0x3f80, (short)0x3f80};

    // staging role: thread t handles rows srow, srow+32; 16B segment sseg
    const int srow = t >> 3, sseg = t & 7;

    for (int rep = 0; rep < NREP; ++rep) {
        float* outb = (rep == 0 ? out : outdup) + (size_t)batch * TLEN * DD;

        // Q B-fragments: B[kk=d][n=q=l15]
        bf16x8 qf[2];
        #pragma unroll
        for (int s = 0; s < 2; ++s)
            qf[s] = ld16(Qb + (size_t)(qb + qt * 16 + l15) * DD + s * 32 + quad * 8);

        f32x4 o_acc[4];
        #pragma unroll
        for (int nt = 0; nt < 4; ++nt) o_acc[nt] = f32x4{0.f, 0.f, 0.f, 0.f};
        f32x4 lD = f32x4{0.f, 0.f, 0.f, 0.f};

        // prefetch chunk 0 into VGPRs (fully coalesced 16B loads)
        uint4 ka, kb4, va, vb4;
        {
            const ushort* kp = Kb + (size_t)srow * DD + sseg * 8;
            ka  = *(const uint4*)kp;
            kb4 = *(const uint4*)(kp + 32 * DD);
            const ushort* vp = Vb + (size_t)srow * TLEN + sseg * 8;
            va  = *(const uint4*)vp;
            vb4 = *(const uint4*)(vp + 32 * TLEN);
        }

        for (int ci = 0; ci < nc; ++ci) {
            const int c0 = ci * 64;
            __syncthreads();                        // prev chunk fully consumed
            *(uint4*)&Kl[srow * 72 + sseg * 8]        = ka;
            *(uint4*)&Kl[(srow + 32) * 72 + sseg * 8] = kb4;
            *(uint4*)&Vt[srow * 72 + sseg * 8]        = va;
            *(uint4*)&Vt[(srow + 32) * 72 + sseg * 8] = vb4;
            __syncthreads();

            if (ci + 1 < nc) {                      // prefetch next chunk
                const int c1 = c0 + 64;
                const ushort* kp = Kb + (size_t)(c1 + srow) * DD + sseg * 8;
                ka  = *(const uint4*)kp;
                kb4 = *(const uint4*)(kp + 32 * DD);
                const ushort* vp = Vb + (size_t)srow * TLEN + c1 + sseg * 8;
                va  = *(const uint4*)vp;
                vb4 = *(const uint4*)(vp + 32 * TLEN);
            }

            // K A-fragments from LDS: A[m=key][kk=d]
            bf16x8 kf[2][2];
            #pragma unroll
            for (int kt2 = 0; kt2 < 2; ++kt2)
                #pragma unroll
                for (int s = 0; s < 2; ++s)
                    kf[kt2][s] = ld16(&Kl[(g * 32 + kt2 * 16 + l15) * 72 + s * 32 + quad * 8]);

            // S^T: rows = keys, cols = queries
            f32x4 st[2];
            st[0] = f32x4{0.f, 0.f, 0.f, 0.f};
            st[1] = f32x4{0.f, 0.f, 0.f, 0.f};
            #pragma unroll
            for (int s = 0; s < 2; ++s)
                #pragma unroll
                for (int kt2 = 0; kt2 < 2; ++kt2)
                    st[kt2] = __builtin_amdgcn_mfma_f32_16x16x32_bf16(
                        kf[kt2][s], qf[s], st[kt2], 0, 0, 0);

            // V B-fragments: B[kk=key][n=d]
            bf16x8 vf[4];
            #pragma unroll
            for (int nt = 0; nt < 4; ++nt)
                vf[nt] = ld16(&Vt[(nt * 16 + l15) * 72 + g * 32 + quad * 8]);

            // softmax weights -> Pw (wave-private); l handled by ones-MFMA
            ushort* pwb = &Pw[w][l15 * 36 + quad * 4];
            if (ci == nc - 1) {
                const int q = qb + qt * 16 + l15;
                #pragma unroll
                for (int kt2 = 0; kt2 < 2; ++kt2) {
                    const int kbase = c0 + g * 32 + kt2 * 16 + quad * 4;
                    float p[4];
                    #pragma unroll
                    for (int r = 0; r < 4; ++r) {
                        float e = exp2f(st[kt2][r]);
                        p[r] = (kbase + r <= q) ? e : 0.f;
                    }
                    *(uint*)&pwb[kt2 * 16]     = pk2(p[0], p[1]);
                    *(uint*)&pwb[kt2 * 16 + 2] = pk2(p[2], p[3]);
                }
            } else {
                #pragma unroll
                for (int kt2 = 0; kt2 < 2; ++kt2) {
                    *(uint*)&pwb[kt2 * 16]     = pk2(exp2f(st[kt2][0]), exp2f(st[kt2][1]));
                    *(uint*)&pwb[kt2 * 16 + 2] = pk2(exp2f(st[kt2][2]), exp2f(st[kt2][3]));
                }
            }

            // O += P.V ; l += P.1  (A[m=q][kk=key 0..31], one ld8x2)
            bf16x8 ap = ld8x2(&Pw[w][l15 * 36 + quad * 8]);
            #pragma unroll
            for (int nt = 0; nt < 4; ++nt)
                o_acc[nt] = __builtin_amdgcn_mfma_f32_16x16x32_bf16(
                    ap, vf[nt], o_acc[nt], 0, 0, 0);
            lD = __builtin_amdgcn_mfma_f32_16x16x32_bf16(ap, onesf, lD, 0, 0, 0);
        }

        // lD[r] = l for q = quad*4+r (replicated over l15) — same indexing as
        // o_acc rows, so no cross-lane reduction needed.
        if (g == 1) {
            #pragma unroll
            for (int nt = 0; nt < 4; ++nt)
                #pragma unroll
                for (int r = 0; r < 4; ++r)
                    Ob[qt][(quad * 4 + r) * 64 + nt * 16 + l15] = o_acc[nt][r];
            if (l15 == 0) {
                #pragma unroll
                for (int r = 0; r < 4; ++r) lb[qt][quad * 4 + r] = lD[r];
            }
        }
        __syncthreads();
        if (g == 0) {
            float linv[4];
            #pragma unroll
            for (int r = 0; r < 4; ++r)
                linv[r] = __builtin_amdgcn_rcpf(lD[r] + lb[qt][quad * 4 + r]);
            #pragma unroll
            for (int nt = 0; nt < 4; ++nt)
                #pragma unroll
                for (int r = 0; r < 4; ++r) {
                    float v = o_acc[nt][r] + Ob[qt][(quad * 4 + r) * 64 + nt * 16 + l15];
                    outb[(size_t)(qb + qt * 16 + quad * 4 + r) * DD + nt * 16 + l15] = v * linv[r];
                }
        }
        __syncthreads();   // Ob/lb safe for next rep
    }
}

extern "C" void kernel_launch(void* const* d_in, const int* in_sizes, int n_in,
                              void* d_out, int out_size, void* d_ws, size_t ws_size,
                              hipStream_t stream) {
    const float* y  = (const float*)d_in[0];
    const float* Wq = (const float*)d_in[1];
    const float* Wk = (const float*)d_in[2];
    const float* Wv = (const float*)d_in[3];
    float* outp = (float*)d_out;

    const int rows = in_sizes[0] / NINP;       // B*T = 16384
    const int nb = rows / TLEN;                // batches = 4

    ushort* WT  = (ushort*)d_ws;               // 3*16384 bf16
    ushort* Qh  = WT + 3 * 16384;
    ushort* Kh  = Qh + (size_t)rows * DD;
    ushort* VhT = Kh + (size_t)rows * DD;      // [b][d][t]
    float* scratch = (float*)(VhT + (size_t)rows * DD);   // probe dup output

    prep_wt<<<48, 256, 0, stream>>>(Wq, Wk, Wv, WT);
    qkv_kernel<<<rows / 32, 256, 0, stream>>>(y, WT, Qh, Kh, VhT);
    attn_kernel<<<nb * 128, 256, 0, stream>>>(Qh, Kh, VhT, outp, scratch);
}